// Round 10
// baseline (2083.486 us; speedup 1.0000x reference)
//
#include <hip/hip_runtime.h>
#include <math.h>

typedef unsigned short u16;
typedef unsigned int   u32;
typedef __bf16  bf16x8 __attribute__((ext_vector_type(8)));
typedef float   f32x4  __attribute__((ext_vector_type(4)));

#define Bz   8
#define Tz   512
#define Dz   1024
#define Hz   16
#define KVHz 4
#define HDz  64
#define Lz   4
#define Vz   32000
#define FFz  4096
#define Mz   (Bz*Tz)        // 4096
#define QKVz (Hz*HDz + 2*KVHz*HDz)  // 1536

// ---------- helpers ----------
__device__ __forceinline__ u16 bf16r(float f) {          // round-to-nearest-even fp32->bf16
    u32 u = __builtin_bit_cast(u32, f);
    u += 0x7fffu + ((u >> 16) & 1u);
    return (u16)(u >> 16);
}
__device__ __forceinline__ float b2f(u16 u) {
    u32 v = ((u32)u) << 16;
    return __builtin_bit_cast(float, v);
}
__device__ __forceinline__ float fast_erf(float x) {     // A&S 7.1.26, |err|<1.5e-7
    const float ax = fabsf(x);
    const float t  = 1.f / (1.f + 0.3275911f * ax);
    const float y  = t * (0.254829592f + t * (-0.284496736f + t * (1.421413741f +
                     t * (-1.453152027f + t * 1.061405429f))));
    const float r  = 1.f - y * __expf(-ax * ax);
    return copysignf(r, x);
}
__device__ __forceinline__ void glds16(const void* g, void* l) {
    // async global->LDS, 16B per lane; LDS dest = wave-uniform base + lane*16
    __builtin_amdgcn_global_load_lds(
        (__attribute__((address_space(1))) unsigned int*)(unsigned long long)g,
        (__attribute__((address_space(3))) unsigned int*)l, 16, 0, 0);
}

// ---------- embedding gather ----------
__global__ __launch_bounds__(256) void embed_kernel(const int* __restrict__ ids,
                                                    const float* __restrict__ wte,
                                                    float* __restrict__ x) {
    const int row = blockIdx.x;
    const int id  = ids[row];
    ((float4*)(x + (size_t)row * Dz))[threadIdx.x] =
        ((const float4*)(wte + (size_t)id * Dz))[threadIdx.x];
}

// ---------- fp32 [K][N] -> bf16 [N][K] transpose+convert ----------
__global__ __launch_bounds__(256) void transpose_cvt_kernel(const float* __restrict__ in,
                                                            u16* __restrict__ out,
                                                            int K, int N) {
    __shared__ float tile[64][65];
    const size_t lofs = (size_t)blockIdx.z * (size_t)K * (size_t)N;
    const float* inp = in + lofs;
    u16* outp = out + lofs;
    const int nt = blockIdx.x << 6, kt = blockIdx.y << 6;
    const int c4 = (threadIdx.x & 15) << 2;
    const int r0 = threadIdx.x >> 4;
#pragma unroll
    for (int rr = 0; rr < 64; rr += 16) {
        const int r = rr + r0;
        float4 v = *(const float4*)(inp + (size_t)(kt + r) * N + nt + c4);
        tile[r][c4] = v.x; tile[r][c4 + 1] = v.y; tile[r][c4 + 2] = v.z; tile[r][c4 + 3] = v.w;
    }
    __syncthreads();
    const int n0 = threadIdx.x >> 2;
    const int kk = (threadIdx.x & 3) << 4;
    u16* ob = outp + (size_t)(nt + n0) * K + kt + kk;
#pragma unroll
    for (int g = 0; g < 4; ++g) {
        ushort4 uo;
        uo.x = bf16r(tile[kk + g * 4 + 0][n0]);
        uo.y = bf16r(tile[kk + g * 4 + 1][n0]);
        uo.z = bf16r(tile[kk + g * 4 + 2][n0]);
        uo.w = bf16r(tile[kk + g * 4 + 3][n0]);
        *(ushort4*)(ob + g * 4) = uo;
    }
}

// ---------- layernorm (fp32 in -> bf16 out) ----------
__global__ __launch_bounds__(256) void ln_kernel(const float* __restrict__ x,
                                                 const float* __restrict__ g,
                                                 const float* __restrict__ bb,
                                                 u16* __restrict__ out) {
    const int row = blockIdx.x;
    const float4 v = ((const float4*)(x + (size_t)row * Dz))[threadIdx.x];
    float s = v.x + v.y + v.z + v.w;
    float q = v.x * v.x + v.y * v.y + v.z * v.z + v.w * v.w;
#pragma unroll
    for (int m = 32; m > 0; m >>= 1) { s += __shfl_xor(s, m, 64); q += __shfl_xor(q, m, 64); }
    __shared__ float ss[4], qq[4];
    const int wid = threadIdx.x >> 6, lane = threadIdx.x & 63;
    if (lane == 0) { ss[wid] = s; qq[wid] = q; }
    __syncthreads();
    s = ss[0] + ss[1] + ss[2] + ss[3];
    q = qq[0] + qq[1] + qq[2] + qq[3];
    const float mean = s * (1.f / 1024.f);
    const float rstd = rsqrtf(q * (1.f / 1024.f) - mean * mean + 1e-5f);
    const float4 gv = ((const float4*)g)[threadIdx.x];
    const float4 bv = ((const float4*)bb)[threadIdx.x];
    ushort4 o;
    o.x = bf16r((v.x - mean) * rstd * gv.x + bv.x);
    o.y = bf16r((v.y - mean) * rstd * gv.y + bv.y);
    o.z = bf16r((v.z - mean) * rstd * gv.z + bv.z);
    o.w = bf16r((v.w - mean) * rstd * gv.w + bv.w);
    ((ushort4*)(out + (size_t)row * Dz))[threadIdx.x] = o;
}

// ---------- qkv fp32 -> rope'd q/k + v, bf16 ----------
// q: [b][h][t][d] (pre-scaled 1/8); k: [b][kvh][t][d]; v: TRANSPOSED [b][kvh][d][t]
__global__ __launch_bounds__(256) void rope_split_kernel(const float* __restrict__ qkv,
                                                         u16* __restrict__ q,
                                                         u16* __restrict__ k,
                                                         u16* __restrict__ vt) {
    const int row = blockIdx.x;            // b*T + t
    const int b = row >> 9, t = row & 511;
    const float* src = qkv + (size_t)row * QKVz;
    const float ft = (float)t;
    for (int p = threadIdx.x; p < 512; p += 256) {   // q: 16 heads x 32 pairs
        const int h = p >> 5, i = p & 31;
        const float e = src[h * 64 + 2 * i], o = src[h * 64 + 2 * i + 1];
        const float ang = ft * exp2f((float)i * -0.41524101186092029f); // 10000^(-2i/64)
        float sn, cs; sincosf(ang, &sn, &cs);
        const size_t qi = (size_t)((b * 16 + h) * 512 + t) * 64 + 2 * i;
        q[qi]     = bf16r((e * cs - o * sn) * 0.125f);   // fold 1/sqrt(HD)
        q[qi + 1] = bf16r((e * sn + o * cs) * 0.125f);
    }
    for (int p = threadIdx.x; p < 128; p += 256) {   // k: 4 kv-heads x 32 pairs
        const int h = p >> 5, i = p & 31;
        const float e = src[1024 + h * 64 + 2 * i], o = src[1024 + h * 64 + 2 * i + 1];
        const float ang = ft * exp2f((float)i * -0.41524101186092029f);
        float sn, cs; sincosf(ang, &sn, &cs);
        const size_t ki = (size_t)((b * 4 + h) * 512 + t) * 64 + 2 * i;
        k[ki]     = bf16r(e * cs - o * sn);
        k[ki + 1] = bf16r(e * sn + o * cs);
    }
    for (int p = threadIdx.x; p < 128; p += 256) {   // v: no rope; store d-major (V^T)
        const int h = p >> 5, i = p & 31;
        const float e = src[1280 + 2 * p], o = src[1280 + 2 * p + 1];
        const size_t vbase = (size_t)(b * 4 + h) * (64 * 512);
        vt[vbase + (size_t)(2 * i)     * 512 + t] = bf16r(e);
        vt[vbase + (size_t)(2 * i + 1) * 512 + t] = bf16r(o);
    }
}

// ---------- MFMA flash attention ----------
// Block = (b, h, 64-row q-tile); 4 independent waves x 16 q-rows; no block barriers
// (per-wave private P_lds, causal trip counts differ per wave).
__global__ __launch_bounds__(256) void attn_kernel(const u16* __restrict__ q,
                                                   const u16* __restrict__ k,
                                                   const u16* __restrict__ vt,
                                                   u16* __restrict__ y) {
    __shared__ __align__(16) u16 plds[4][16 * 40];
    const int tid = threadIdx.x;
    const int w = tid >> 6, lane = tid & 63;
    const int l15 = lane & 15, g = lane >> 4;

    const int bid = blockIdx.x;            // b*128 + h*8 + qt
    const int qt = bid & 7, h = (bid >> 3) & 15, b = bid >> 7;
    const int kvh = h >> 2;
    const int q0 = qt * 64 + w * 16;       // this wave's 16 q-rows
    const u16* qbase  = q  + ((size_t)(b * 16 + h)  * 512 + q0) * 64;
    const u16* kbase  = k  + (size_t)(b * 4 + kvh) * (512 * 64);
    const u16* vtbase = vt + (size_t)(b * 4 + kvh) * (64 * 512);

    // Q fragments (row = l15, d-chunks 0/1)
    const bf16x8 qf0 = *(const bf16x8*)(qbase + (size_t)l15 * 64 + g * 8);
    const bf16x8 qf1 = *(const bf16x8*)(qbase + (size_t)l15 * 64 + 32 + g * 8);

    f32x4 so[4];                            // O acc, dtiles of 16
#pragma unroll
    for (int dt = 0; dt < 4; ++dt) so[dt] = (f32x4){0.f, 0.f, 0.f, 0.f};
    float m[4]    = {-1e30f, -1e30f, -1e30f, -1e30f};
    float lsum[4] = {0.f, 0.f, 0.f, 0.f};
    const int qrow = q0 + g * 4;            // + r = this lane's q rows (D layout)
    u16* pw = &plds[w][0];

    const int nch = ((q0 + 15) >> 5) + 1;   // causal: 32-wide kv chunks
    for (int c = 0; c < nch; ++c) {
        const int kc = c << 5;
        // K fragments: kv-tiles lo (kc..kc+15) and hi (kc+16..kc+31)
        const u16* kp = kbase + (size_t)(kc + l15) * 64 + g * 8;
        const bf16x8 kl0 = *(const bf16x8*)(kp);
        const bf16x8 kl1 = *(const bf16x8*)(kp + 32);
        const bf16x8 kh0 = *(const bf16x8*)(kp + 16 * 64);
        const bf16x8 kh1 = *(const bf16x8*)(kp + 16 * 64 + 32);
        f32x4 slo = (f32x4){0.f, 0.f, 0.f, 0.f};
        f32x4 shi = (f32x4){0.f, 0.f, 0.f, 0.f};
        slo = __builtin_amdgcn_mfma_f32_16x16x32_bf16(qf0, kl0, slo, 0, 0, 0);
        slo = __builtin_amdgcn_mfma_f32_16x16x32_bf16(qf1, kl1, slo, 0, 0, 0);
        shi = __builtin_amdgcn_mfma_f32_16x16x32_bf16(qf0, kh0, shi, 0, 0, 0);
        shi = __builtin_amdgcn_mfma_f32_16x16x32_bf16(qf1, kh1, shi, 0, 0, 0);
        // V^T fragments for PV (issue early; consumed after softmax)
        bf16x8 vf[4];
#pragma unroll
        for (int dt = 0; dt < 4; ++dt)
            vf[dt] = *(const bf16x8*)(vtbase + (size_t)(dt * 16 + l15) * 512 + kc + g * 8);
        // causal mask (D layout: col=l15=kv, row=qrow+r)
        const int kvlo = kc + l15, kvhi = kvlo + 16;
#pragma unroll
        for (int r = 0; r < 4; ++r) {
            const int qg = qrow + r;
            if (kvlo > qg) slo[r] = -1e30f;
            if (kvhi > qg) shi[r] = -1e30f;
        }
        // online softmax (row reduce across the 16 col-lanes)
        float pe0[4], pe1[4], alpha[4];
#pragma unroll
        for (int r = 0; r < 4; ++r) {
            float t = fmaxf(slo[r], shi[r]);
#pragma unroll
            for (int mm = 8; mm > 0; mm >>= 1) t = fmaxf(t, __shfl_xor(t, mm, 64));
            const float mnew = fmaxf(m[r], t);
            pe0[r] = __expf(slo[r] - mnew);
            pe1[r] = __expf(shi[r] - mnew);
            float cs = pe0[r] + pe1[r];
#pragma unroll
            for (int mm = 8; mm > 0; mm >>= 1) cs += __shfl_xor(cs, mm, 64);
            alpha[r] = __expf(m[r] - mnew);
            lsum[r] = lsum[r] * alpha[r] + cs;
            m[r] = mnew;
        }
#pragma unroll
        for (int dt = 0; dt < 4; ++dt)
#pragma unroll
            for (int r = 0; r < 4; ++r) so[dt][r] *= alpha[r];
        // P -> LDS (row = g*4+r, cols l15 / l15+16), then read back as A-frag
#pragma unroll
        for (int r = 0; r < 4; ++r) {
            pw[(g * 4 + r) * 40 + l15]      = bf16r(pe0[r]);
            pw[(g * 4 + r) * 40 + 16 + l15] = bf16r(pe1[r]);
        }
        asm volatile("s_waitcnt lgkmcnt(0)" ::: "memory");  // cross-lane P visibility
        __builtin_amdgcn_sched_barrier(0);                  // rule #18 (cross-lane dep
                                                            // invisible to compiler)
        const bf16x8 pf = *(const bf16x8*)(pw + l15 * 40 + g * 8);
#pragma unroll
        for (int dt = 0; dt < 4; ++dt)
            so[dt] = __builtin_amdgcn_mfma_f32_16x16x32_bf16(pf, vf[dt], so[dt], 0, 0, 0);
        asm volatile("" ::: "memory");      // keep next iter's P writes after this read
    }
    // epilogue: y[b][t][h*64+d]
#pragma unroll
    for (int dt = 0; dt < 4; ++dt) {
#pragma unroll
        for (int r = 0; r < 4; ++r) {
            const int qg = qrow + r;
            y[(size_t)(b * 512 + qg) * 1024 + h * 64 + dt * 16 + l15] =
                bf16r(so[dt][r] / lsum[r]);
        }
    }
}

// ---------- 128-tile bf16 MFMA GEMM (qkv/proj/mlp) ----------
// EPI: 0 = +bias -> f32 | 1 = +bias+resid -> f32
template <int EPI>
__global__ __launch_bounds__(256) void gemm_kernel(const u16* __restrict__ A,
                                                   const u16* __restrict__ Bt,
                                                   const float* __restrict__ bias,
                                                   const float* __restrict__ resid,
                                                   float* __restrict__ outF,
                                                   u16* __restrict__ outU,
                                                   int N, int K) {
    __shared__ __align__(16) u16 lA[3][4096];   // 3 bufs x (4 kc-chunks x 128 rows x 8 bf16)
    __shared__ __align__(16) u16 lB[3][4096];
    const int tid = threadIdx.x;
    const int wid = tid >> 6, lane = tid & 63;

    // --- GROUP_M=8 swizzle (gridDim.y == 32 for all our GEMMs) ---
    const int ntx = gridDim.x;
    const int bid = blockIdx.y * ntx + blockIdx.x;
    const int gsz = ntx << 3;                   // 8 m-tiles x all n-tiles
    const int g   = bid / gsz;
    const int rem = bid - g * gsz;
    const int m0 = ((g << 3) + (rem & 7)) << 7; // m fastest within group
    const int n0 = (rem >> 3) << 7;

    const int wm = (wid >> 1) << 6, wn = (wid & 1) << 6;
    const int kc = lane >> 4, l15 = lane & 15;

    const u16* gA = A  + (size_t)(m0 + (tid & 127)) * K + ((tid >> 7) << 3);
    const u16* gB = Bt + (size_t)(n0 + (tid & 127)) * K + ((tid >> 7) << 3);
    const int wofs = wid << 9;

    f32x4 acc[4][4];
#pragma unroll
    for (int i = 0; i < 4; ++i)
#pragma unroll
        for (int j = 0; j < 4; ++j) acc[i][j] = (f32x4){0.f, 0.f, 0.f, 0.f};

    auto stage = [&](int c) {
        glds16(gA, &lA[c][wofs]); glds16(gA + 16, &lA[c][2048 + wofs]);
        glds16(gB, &lB[c][wofs]); glds16(gB + 16, &lB[c][2048 + wofs]);
        gA += 32; gB += 32;
    };
    auto compute = [&](int c) {
        const bf16x8* lAv = (const bf16x8*)lA[c];
        const bf16x8* lBv = (const bf16x8*)lB[c];
        bf16x8 af[4], bfr[4];
#pragma unroll
        for (int tt = 0; tt < 4; ++tt) {
            af[tt]  = lAv[kc * 128 + wm + tt * 16 + l15];
            bfr[tt] = lBv[kc * 128 + wn + tt * 16 + l15];
        }
        __builtin_amdgcn_s_setprio(1);
#pragma unroll
        for (int tm = 0; tm < 4; ++tm)
#pragma unroll
            for (int tn = 0; tn < 4; ++tn)
                acc[tm][tn] = __builtin_amdgcn_mfma_f32_16x16x32_bf16(af[tm], bfr[tn],
                                                                      acc[tm][tn], 0, 0, 0);
        __builtin_amdgcn_s_setprio(0);
    };

    const int nk = K >> 5;
    stage(0); stage(1);

    int cb = 0, sb = 2;
    for (int t = 0; t < nk - 1; ++t) {
        asm volatile("s_waitcnt vmcnt(4)" ::: "memory");
        __builtin_amdgcn_s_barrier();
        if (t + 2 < nk) stage(sb);
        compute(cb);
        cb = (cb == 2) ? 0 : cb + 1;
        sb = (sb == 2) ? 0 : sb + 1;
    }
    asm volatile("s_waitcnt vmcnt(0)" ::: "memory");
    __builtin_amdgcn_s_barrier();
    compute(cb);

    const int rbase = (lane >> 4) << 2;
#pragma unroll
    for (int tn = 0; tn < 4; ++tn) {
        const int gc = n0 + wn + tn * 16 + l15;
        float bv = 0.f;
        if (EPI != 3) bv = bias[gc];
#pragma unroll
        for (int tm = 0; tm < 4; ++tm) {
#pragma unroll
            for (int r = 0; r < 4; ++r) {
                const int gr = m0 + wm + tm * 16 + rbase + r;
                const size_t idx = (size_t)gr * N + gc;
                float vv = acc[tm][tn][r] + bv;
                if (EPI == 1) vv += resid[idx];
                if (EPI == 2) {
                    const float gl = 0.5f * vv * (1.f + fast_erf(vv * 0.70710678118654752f));
                    outU[idx] = bf16r(gl);
                } else {
                    outF[idx] = vv;
                }
            }
        }
    }
}

// ---------- 256x256 MERGED-4-PHASE bf16 MFMA GEMM (fc) ----------
#define PHASE2(c, kh, STAGE)                                                   \
  {                                                                            \
    bf16x8 af[8], bfr[4];                                                      \
    _Pragma("unroll") for (int j = 0; j < 8; ++j)                              \
      af[j] = smv[(c) * 4096 + (kh) * 512 + aoff + j * 16];                    \
    _Pragma("unroll") for (int n = 0; n < 4; ++n)                              \
      bfr[n] = smv[(c) * 4096 + (kh) * 512 + boff + n * 16];                   \
    STAGE;                                                                     \
    __builtin_amdgcn_s_barrier();                                              \
    asm volatile("s_waitcnt lgkmcnt(0)" ::: "memory");                         \
    __builtin_amdgcn_s_setprio(1);                                             \
    _Pragma("unroll") for (int j = 0; j < 8; ++j)                              \
      _Pragma("unroll") for (int n = 0; n < 4; ++n)                            \
        acc[j][n] = __builtin_amdgcn_mfma_f32_16x16x32_bf16(                   \
            af[j], bfr[n], acc[j][n], 0, 0, 0);                                \
    __builtin_amdgcn_s_setprio(0);                                             \
    asm volatile("s_waitcnt vmcnt(8)" ::: "memory");                           \
    __builtin_amdgcn_s_barrier();                                              \
  }

template <int EPI>
__global__ __launch_bounds__(512) void gemm256_kernel(const u16* __restrict__ A,
                                                      const u16* __restrict__ Bt,
                                                      const float* __restrict__ bias,
                                                      float* __restrict__ outF,
                                                      u16* __restrict__ outU,
                                                      int N, int K) {
    const int NTt = N >> 8;                     // n-tiles
    const int bid = blockIdx.x;
    const int xcd = bid & 7;
    const int window = bid >> 8;
    const int pos = (bid >> 3) & 31;            // 32 concurrent slots per XCD
    const int strip = xcd & 3;                  // XCD's fixed m-strip (4 m-tiles)
    const int scol = (xcd >> 2) + (window << 1);
    const int mt = (strip << 2) + (pos & 3);    // m-minor within supertile
    const int nt = (scol << 3) + (pos >> 2);
    if (nt >= NTt) return;                      // grid padding (partial last scol)
    const int m0 = mt << 8, n0 = nt << 8;

    __shared__ __align__(16) u16 sm[65536];     // 128 KiB: Ab0|Bb0|Ab1|Bb1, 2048 units each
    const int tid = threadIdx.x;
    const int wid = tid >> 6, lane = tid & 63;
    const int wr = wid >> 2, wc = wid & 3;      // 2M x 4N waves, wave tile 128x64
    const int kc = lane >> 4, l15 = lane & 15;

    const int s_kc  = wid >> 1;
    const int s_row = ((wid & 1) << 6) + lane;
    const int s_u   = wid << 6;

    const u16* gA0 = A  + (size_t)(m0 + s_row) * K + s_kc * 8;
    const u16* gA1 = gA0 + (size_t)128 * K;
    const u16* gB0 = Bt + (size_t)(n0 + s_row) * K + s_kc * 8;
    const u16* gB1 = gB0 + (size_t)128 * K;

    f32x4 acc[8][4];
#pragma unroll
    for (int i = 0; i < 8; ++i)
#pragma unroll
        for (int j = 0; j < 4; ++j) acc[i][j] = (f32x4){0.f, 0.f, 0.f, 0.f};

    const bf16x8* smv = (const bf16x8*)sm;
    const int aoff = wr * 1024 + kc * 128 + l15;
    const int boff = 2048 + (wc >> 1) * 1024 + kc * 128 + ((wc & 1) << 6) + l15;

    auto stA = [&](int kt, int kh, int c) {
        const int ko = kt * 64 + kh * 32;
        const int ub = c * 4096 + kh * 512 + s_u;
        glds16(gA0 + ko, &sm[(size_t)ub * 8]);
        glds16(gA1 + ko, &sm[(size_t)(ub + 1024) * 8]);
    };
    auto stB = [&](int kt, int kh, int c) {
        const int ko = kt * 64 + kh * 32;
        const int ub = 2048 + c * 4096 + kh * 512 + s_u;
        glds16(gB0 + ko, &sm[(size_t)ub * 8]);
        glds16(gB1 + ko, &sm[(size_t)(ub + 1024) * 8]);
    };

    const int nk = K >> 6;
    stA(0, 0, 0); stB(0, 0, 0);
    stA(0, 1, 0); stB(0, 1, 0);
    stA(1, 0, 1); stB(1, 0, 1);
    asm volatile("s_waitcnt vmcnt(4)" ::: "memory");
    __builtin_amdgcn_s_barrier();

    const int niter = nk >> 1;
    for (int i = 0; i < niter; ++i) {
        const int t1 = 2 * i + 1;
        const int t2 = (2 * i + 2 < nk) ? 2 * i + 2 : nk - 1;
        const int t3 = (2 * i + 3 < nk) ? 2 * i + 3 : nk - 1;
        PHASE2(0, 0, { stA(t1, 1, 1); stB(t1, 1, 1); })
        PHASE2(0, 1, { stA(t2, 0, 0); stB(t2, 0, 0); })
        PHASE2(1, 0, { stA(t2, 1, 0); stB(t2, 1, 0); })
        PHASE2(1, 1, { stA(t3, 0, 1); stB(t3, 0, 1); })
    }
    asm volatile("s_waitcnt vmcnt(0)" ::: "memory");

    const int rbase = (lane >> 4) << 2;
#pragma unroll
    for (int n = 0; n < 4; ++n) {
        const int gc = n0 + wc * 64 + n * 16 + l15;
        float bv = 0.f;
        if (EPI == 2) bv = bias[gc];
#pragma unroll
        for (int f = 0; f < 8; ++f) {
#pragma unroll
            for (int r = 0; r < 4; ++r) {
                const int gr = m0 + wr * 128 + f * 16 + rbase + r;
                const size_t idx = (size_t)gr * N + gc;
                float vv = acc[f][n][r] + bv;
                if (EPI == 2) {
                    const float gl = 0.5f * vv * (1.f + fast_erf(vv * 0.70710678118654752f));
                    outU[idx] = bf16r(gl);
                } else {
                    outF[idx] = vv;
                }
            }
        }
    }
}

// ---------- 256x128 BK=32 bf16 MFMA GEMM, 2 blocks/CU (lm_head) ----------
// R10: sized for occupancy-2 (TLP overlap across co-resident blocks):
// LDS 48 KB (2 buf x {A 16KB + B 8KB}), 8 waves (4M x 2N, wave tile 64x64,
// acc = 64 VGPR), __launch_bounds__(512,4) caps regs at 128 -> 16 waves/CU.
// Per K-tile: {8 ds_read_b128 -> lgkm(0) -> barrier -> stage(t+2: 3 glds into
// just-freed buf) -> 16 MFMA -> vmcnt(3) [t+1 landed; only t+2 in flight] ->
// barrier}. One block's LDS/stage/epilogue overlaps the other's MFMA (m114).
// Grid: 1-D, m fastest (16 m-tiles = M/256 share each B panel; A 8MB L2/L3-res).
template <int EPI>
__global__ __launch_bounds__(512, 4) void gemm_k2_kernel(const u16* __restrict__ A,
                                                         const u16* __restrict__ Bt,
                                                         const float* __restrict__ bias,
                                                         float* __restrict__ outF,
                                                         u16* __restrict__ outU,
                                                         int N, int K) {
    __shared__ __align__(16) u16 sm[2][12288];  // per buf: A units [0,1024), B [1024,1536)
    const int tid = threadIdx.x;
    const int wid = tid >> 6, lane = tid & 63;
    const int wr = wid >> 1, wc = wid & 1;      // 4M x 2N waves
    const int kcl = lane >> 4, l15 = lane & 15;

    const int bid = blockIdx.x;                 // m fastest: 16 m-tiles per n-tile
    const int m0 = (bid & 15) << 8;
    const int n0 = (bid >> 4) << 7;

    // staging geometry: A units [kc(4)][row(256)], two runs (kc 0-1, 2-3);
    //                   B units [kc(4)][row(128)], one run.
    const u16* gA = A  + (size_t)(m0 + ((wid & 3) << 6) + lane) * K + ((wid >> 2) << 3);
    const u16* gB = Bt + (size_t)(n0 + ((wid & 1) << 6) + lane) * K + ((wid >> 1) << 3);
    const int widu = wid << 9;                  // wid*64 units * 8 u16

    f32x4 acc[4][4];
#pragma unroll
    for (int i = 0; i < 4; ++i)
#pragma unroll
        for (int j = 0; j < 4; ++j) acc[i][j] = (f32x4){0.f, 0.f, 0.f, 0.f};

    const bf16x8* smv = (const bf16x8*)sm;
    const int abase = kcl * 256 + wr * 64 + l15;          // + c*1536
    const int bbase = 1024 + kcl * 128 + wc * 64 + l15;

    auto stage = [&](int kt, int c) {           // 3 glds
        const int ko = kt << 5;
        glds16(gA + ko,      &sm[c][widu]);
        glds16(gA + ko + 16, &sm[c][4096 + widu]);
        glds16(gB + ko,      &sm[c][8192 + widu]);
    };

    const int nk = K >> 5;                      // 32 K-tiles
    stage(0, 0); stage(1, 1);                   // 6 glds outstanding
    asm volatile("s_waitcnt vmcnt(3)" ::: "memory");      // tile 0 landed
    __builtin_amdgcn_s_barrier();

    int cur = 0;
    for (int t = 0; t < nk; ++t) {
        bf16x8 af[4], bf[4];
#pragma unroll
        for (int j = 0; j < 4; ++j) af[j] = smv[cur * 1536 + abase + j * 16];
#pragma unroll
        for (int n = 0; n < 4; ++n) bf[n] = smv[cur * 1536 + bbase + n * 16];
        asm volatile("s_waitcnt lgkmcnt(0)" ::: "memory");
        __builtin_amdgcn_s_barrier();           // all waves done reading buf[cur]
        const bool pre = (t + 2 < nk);
        if (pre) stage(t + 2, cur);             // WAR-safe: overwrite just-freed buf
        __builtin_amdgcn_s_setprio(1);
#pragma unroll
        for (int j = 0; j < 4; ++j)
#pragma unroll
            for (int n = 0; n < 4; ++n)
                acc[j][n] = __builtin_amdgcn_mfma_f32_16x16x32_bf16(af[j], bf[n],
                                                                    acc[j][n], 0, 0, 0);
        __builtin_amdgcn_s_setprio(0);
        if (pre) { asm volatile("s_waitcnt vmcnt(3)" ::: "memory"); }   // t+1 landed
        else     { asm volatile("s_waitcnt vmcnt(0)" ::: "memory"); }   // tail drain
        __builtin_amdgcn_s_barrier();
        cur ^= 1;
    }

    const int rbase = kcl << 2;
#pragma unroll
    for (int n = 0; n < 4; ++n) {
        const int gc = n0 + wc * 64 + n * 16 + l15;
        float bv = 0.f;
        if (EPI == 2) bv = bias[gc];
#pragma unroll
        for (int j = 0; j < 4; ++j) {
#pragma unroll
            for (int r = 0; r < 4; ++r) {
                const int gr = m0 + wr * 64 + j * 16 + rbase + r;
                const size_t idx = (size_t)gr * N + gc;
                float vv = acc[j][n][r] + bv;
                if (EPI == 2) {
                    const float gl = 0.5f * vv * (1.f + fast_erf(vv * 0.70710678118654752f));
                    outU[idx] = bf16r(gl);
                } else {
                    outF[idx] = vv;
                }
            }
        }
    }
}

// ---------- host ----------
extern "C" void kernel_launch(void* const* d_in, const int* in_sizes, int n_in,
                              void* d_out, int out_size, void* d_ws, size_t ws_size,
                              hipStream_t stream) {
    const int*   ids      = (const int*)d_in[0];
    const float* wte      = (const float*)d_in[1];
    const float* ln1_g    = (const float*)d_in[2];
    const float* ln1_b    = (const float*)d_in[3];
    const float* c_attn_w = (const float*)d_in[4];
    const float* c_attn_b = (const float*)d_in[5];
    const float* c_proj_w = (const float*)d_in[6];
    const float* c_proj_b = (const float*)d_in[7];
    const float* ln2_g    = (const float*)d_in[8];
    const float* ln2_b    = (const float*)d_in[9];
    const float* fc_w     = (const float*)d_in[10];
    const float* fc_b     = (const float*)d_in[11];
    const float* proj_w   = (const float*)d_in[12];
    const float* proj_b   = (const float*)d_in[13];
    const float* lnf_g    = (const float*)d_in[14];
    const float* lnf_b    = (const float*)d_in[15];
    const float* lm_w     = (const float*)d_in[16];
    float* out = (float*)d_out;

    char* w = (char*)d_ws;
    auto take = [&](size_t bytes) { void* p = (void*)w; w += (bytes + 255) & ~(size_t)255; return p; };
    u16*   wqkvT = (u16*)take((size_t)Lz * QKVz * Dz * 2);   // [L][1536][1024]
    u16*   wprojT= (u16*)take((size_t)Lz * Dz * Dz * 2);     // [L][1024][1024]
    u16*   wfcT  = (u16*)take((size_t)Lz * FFz * Dz * 2);    // [L][4096][1024]
    u16*   wmlpT = (u16*)take((size_t)Lz * Dz * FFz * 2);    // [L][1024][4096]
    u16*   wlmT  = (u16*)take((size_t)Vz * Dz * 2);          // [32000][1024]
    float* x     = (float*)take((size_t)Mz * Dz * 4);
    u16*   h     = (u16*)take((size_t)Mz * Dz * 2);
    float* qkv   = (float*)take((size_t)Mz * QKVz * 4);
    u16*   qb    = (u16*)take((size_t)Mz * Dz * 2);
    u16*   kb    = (u16*)take((size_t)Bz * KVHz * Tz * HDz * 2);
    u16*   vb    = (u16*)take((size_t)Bz * KVHz * Tz * HDz * 2);
    u16*   yb    = (u16*)take((size_t)Mz * Dz * 2);
    u16*   mb    = (u16*)take((size_t)Mz * FFz * 2);
    (void)ws_size; (void)in_sizes; (void)n_in; (void)out_size;

    const dim3 tb(256);
    transpose_cvt_kernel<<<dim3(QKVz / 64, Dz / 64, Lz), tb, 0, stream>>>(c_attn_w, wqkvT, Dz, QKVz);
    transpose_cvt_kernel<<<dim3(Dz / 64, Dz / 64, Lz), tb, 0, stream>>>(c_proj_w, wprojT, Dz, Dz);
    transpose_cvt_kernel<<<dim3(FFz / 64, Dz / 64, Lz), tb, 0, stream>>>(fc_w, wfcT, Dz, FFz);
    transpose_cvt_kernel<<<dim3(Dz / 64, FFz / 64, Lz), tb, 0, stream>>>(proj_w, wmlpT, FFz, Dz);
    transpose_cvt_kernel<<<dim3(Vz / 64, Dz / 64, 1), tb, 0, stream>>>(lm_w, wlmT, Dz, Vz);

    embed_kernel<<<Mz, tb, 0, stream>>>(ids, wte, x);

    // fc grid (gemm256 supertile): 128 * ceil(NT/8) blocks
    const int fc_grid = 128 * (((FFz / 256) + 7) / 8);   // 256
    // lm grid (gemm_k2): 16 m-tiles x 250 n-tiles, m fastest
    const int lm_grid = (Mz / 256) * (Vz / 128);         // 4000

    for (int l = 0; l < Lz; ++l) {
        ln_kernel<<<Mz, tb, 0, stream>>>(x, ln1_g + l * Dz, ln1_b + l * Dz, h);
        gemm_kernel<0><<<dim3(QKVz / 128, Mz / 128), tb, 0, stream>>>(
            h, wqkvT + (size_t)l * QKVz * Dz, c_attn_b + l * QKVz, nullptr, qkv, nullptr, QKVz, Dz);
        rope_split_kernel<<<Mz, tb, 0, stream>>>(qkv, qb, kb, vb);
        attn_kernel<<<Bz * Hz * (Tz / 64), tb, 0, stream>>>(qb, kb, vb, yb);
        gemm_kernel<1><<<dim3(Dz / 128, Mz / 128), tb, 0, stream>>>(
            yb, wprojT + (size_t)l * Dz * Dz, c_proj_b + l * Dz, x, x, nullptr, Dz, Dz);
        ln_kernel<<<Mz, tb, 0, stream>>>(x, ln2_g + l * Dz, ln2_b + l * Dz, h);
        gemm256_kernel<2><<<dim3(fc_grid), dim3(512), 0, stream>>>(
            h, wfcT + (size_t)l * FFz * Dz, fc_b + l * FFz, nullptr, mb, FFz, Dz);
        gemm_kernel<1><<<dim3(Dz / 128, Mz / 128), tb, 0, stream>>>(
            mb, wmlpT + (size_t)l * Dz * FFz, proj_b + l * Dz, x, x, nullptr, Dz, FFz);
    }
    ln_kernel<<<Mz, tb, 0, stream>>>(x, lnf_g, lnf_b, h);
    gemm_k2_kernel<3><<<dim3(lm_grid), dim3(512), 0, stream>>>(
        h, wlmT, nullptr, out, nullptr, Vz, Dz);
}

// Round 11
// 1914.672 us; speedup vs baseline: 1.0882x; 1.0882x over previous
//
#include <hip/hip_runtime.h>
#include <math.h>

typedef unsigned short u16;
typedef unsigned int   u32;
typedef __bf16  bf16x8 __attribute__((ext_vector_type(8)));
typedef float   f32x4  __attribute__((ext_vector_type(4)));

#define Bz   8
#define Tz   512
#define Dz   1024
#define Hz   16
#define KVHz 4
#define HDz  64
#define Lz   4
#define Vz   32000
#define FFz  4096
#define Mz   (Bz*Tz)        // 4096
#define QKVz (Hz*HDz + 2*KVHz*HDz)  // 1536

// ---------- helpers ----------
__device__ __forceinline__ u16 bf16r(float f) {          // round-to-nearest-even fp32->bf16
    u32 u = __builtin_bit_cast(u32, f);
    u += 0x7fffu + ((u >> 16) & 1u);
    return (u16)(u >> 16);
}
__device__ __forceinline__ float b2f(u16 u) {
    u32 v = ((u32)u) << 16;
    return __builtin_bit_cast(float, v);
}
__device__ __forceinline__ float fast_erf(float x) {     // A&S 7.1.26, |err|<1.5e-7
    const float ax = fabsf(x);
    const float t  = 1.f / (1.f + 0.3275911f * ax);
    const float y  = t * (0.254829592f + t * (-0.284496736f + t * (1.421413741f +
                     t * (-1.453152027f + t * 1.061405429f))));
    const float r  = 1.f - y * __expf(-ax * ax);
    return copysignf(r, x);
}
__device__ __forceinline__ void glds16(const void* g, void* l) {
    // async global->LDS, 16B per lane; LDS dest = wave-uniform base + lane*16
    __builtin_amdgcn_global_load_lds(
        (__attribute__((address_space(1))) unsigned int*)(unsigned long long)g,
        (__attribute__((address_space(3))) unsigned int*)l, 16, 0, 0);
}

// ---------- embedding gather ----------
__global__ __launch_bounds__(256) void embed_kernel(const int* __restrict__ ids,
                                                    const float* __restrict__ wte,
                                                    float* __restrict__ x) {
    const int row = blockIdx.x;
    const int id  = ids[row];
    ((float4*)(x + (size_t)row * Dz))[threadIdx.x] =
        ((const float4*)(wte + (size_t)id * Dz))[threadIdx.x];
}

// ---------- fp32 [K][N] -> bf16 [N][K] transpose+convert ----------
__global__ __launch_bounds__(256) void transpose_cvt_kernel(const float* __restrict__ in,
                                                            u16* __restrict__ out,
                                                            int K, int N) {
    __shared__ float tile[64][65];
    const size_t lofs = (size_t)blockIdx.z * (size_t)K * (size_t)N;
    const float* inp = in + lofs;
    u16* outp = out + lofs;
    const int nt = blockIdx.x << 6, kt = blockIdx.y << 6;
    const int c4 = (threadIdx.x & 15) << 2;
    const int r0 = threadIdx.x >> 4;
#pragma unroll
    for (int rr = 0; rr < 64; rr += 16) {
        const int r = rr + r0;
        float4 v = *(const float4*)(inp + (size_t)(kt + r) * N + nt + c4);
        tile[r][c4] = v.x; tile[r][c4 + 1] = v.y; tile[r][c4 + 2] = v.z; tile[r][c4 + 3] = v.w;
    }
    __syncthreads();
    const int n0 = threadIdx.x >> 2;
    const int kk = (threadIdx.x & 3) << 4;
    u16* ob = outp + (size_t)(nt + n0) * K + kt + kk;
#pragma unroll
    for (int g = 0; g < 4; ++g) {
        ushort4 uo;
        uo.x = bf16r(tile[kk + g * 4 + 0][n0]);
        uo.y = bf16r(tile[kk + g * 4 + 1][n0]);
        uo.z = bf16r(tile[kk + g * 4 + 2][n0]);
        uo.w = bf16r(tile[kk + g * 4 + 3][n0]);
        *(ushort4*)(ob + g * 4) = uo;
    }
}

// ---------- layernorm (fp32 in -> bf16 out) ----------
__global__ __launch_bounds__(256) void ln_kernel(const float* __restrict__ x,
                                                 const float* __restrict__ g,
                                                 const float* __restrict__ bb,
                                                 u16* __restrict__ out) {
    const int row = blockIdx.x;
    const float4 v = ((const float4*)(x + (size_t)row * Dz))[threadIdx.x];
    float s = v.x + v.y + v.z + v.w;
    float q = v.x * v.x + v.y * v.y + v.z * v.z + v.w * v.w;
#pragma unroll
    for (int m = 32; m > 0; m >>= 1) { s += __shfl_xor(s, m, 64); q += __shfl_xor(q, m, 64); }
    __shared__ float ss[4], qq[4];
    const int wid = threadIdx.x >> 6, lane = threadIdx.x & 63;
    if (lane == 0) { ss[wid] = s; qq[wid] = q; }
    __syncthreads();
    s = ss[0] + ss[1] + ss[2] + ss[3];
    q = qq[0] + qq[1] + qq[2] + qq[3];
    const float mean = s * (1.f / 1024.f);
    const float rstd = rsqrtf(q * (1.f / 1024.f) - mean * mean + 1e-5f);
    const float4 gv = ((const float4*)g)[threadIdx.x];
    const float4 bv = ((const float4*)bb)[threadIdx.x];
    ushort4 o;
    o.x = bf16r((v.x - mean) * rstd * gv.x + bv.x);
    o.y = bf16r((v.y - mean) * rstd * gv.y + bv.y);
    o.z = bf16r((v.z - mean) * rstd * gv.z + bv.z);
    o.w = bf16r((v.w - mean) * rstd * gv.w + bv.w);
    ((ushort4*)(out + (size_t)row * Dz))[threadIdx.x] = o;
}

// ---------- qkv fp32 -> rope'd q/k + v, bf16 ----------
// q: [b][h][t][d] (pre-scaled 1/8); k: [b][kvh][t][d]; v: TRANSPOSED [b][kvh][d][t]
__global__ __launch_bounds__(256) void rope_split_kernel(const float* __restrict__ qkv,
                                                         u16* __restrict__ q,
                                                         u16* __restrict__ k,
                                                         u16* __restrict__ vt) {
    const int row = blockIdx.x;            // b*T + t
    const int b = row >> 9, t = row & 511;
    const float* src = qkv + (size_t)row * QKVz;
    const float ft = (float)t;
    for (int p = threadIdx.x; p < 512; p += 256) {   // q: 16 heads x 32 pairs
        const int h = p >> 5, i = p & 31;
        const float e = src[h * 64 + 2 * i], o = src[h * 64 + 2 * i + 1];
        const float ang = ft * exp2f((float)i * -0.41524101186092029f); // 10000^(-2i/64)
        float sn, cs; sincosf(ang, &sn, &cs);
        const size_t qi = (size_t)((b * 16 + h) * 512 + t) * 64 + 2 * i;
        q[qi]     = bf16r((e * cs - o * sn) * 0.125f);   // fold 1/sqrt(HD)
        q[qi + 1] = bf16r((e * sn + o * cs) * 0.125f);
    }
    for (int p = threadIdx.x; p < 128; p += 256) {   // k: 4 kv-heads x 32 pairs
        const int h = p >> 5, i = p & 31;
        const float e = src[1024 + h * 64 + 2 * i], o = src[1024 + h * 64 + 2 * i + 1];
        const float ang = ft * exp2f((float)i * -0.41524101186092029f);
        float sn, cs; sincosf(ang, &sn, &cs);
        const size_t ki = (size_t)((b * 4 + h) * 512 + t) * 64 + 2 * i;
        k[ki]     = bf16r(e * cs - o * sn);
        k[ki + 1] = bf16r(e * sn + o * cs);
    }
    for (int p = threadIdx.x; p < 128; p += 256) {   // v: no rope; store d-major (V^T)
        const int h = p >> 5, i = p & 31;
        const float e = src[1280 + 2 * p], o = src[1280 + 2 * p + 1];
        const size_t vbase = (size_t)(b * 4 + h) * (64 * 512);
        vt[vbase + (size_t)(2 * i)     * 512 + t] = bf16r(e);
        vt[vbase + (size_t)(2 * i + 1) * 512 + t] = bf16r(o);
    }
}

// ---------- MFMA flash attention ----------
// Block = (b, h, 64-row q-tile); 4 independent waves x 16 q-rows; no block barriers
// (per-wave private P_lds, causal trip counts differ per wave).
__global__ __launch_bounds__(256) void attn_kernel(const u16* __restrict__ q,
                                                   const u16* __restrict__ k,
                                                   const u16* __restrict__ vt,
                                                   u16* __restrict__ y) {
    __shared__ __align__(16) u16 plds[4][16 * 40];
    const int tid = threadIdx.x;
    const int w = tid >> 6, lane = tid & 63;
    const int l15 = lane & 15, g = lane >> 4;

    const int bid = blockIdx.x;            // b*128 + h*8 + qt
    const int qt = bid & 7, h = (bid >> 3) & 15, b = bid >> 7;
    const int kvh = h >> 2;
    const int q0 = qt * 64 + w * 16;       // this wave's 16 q-rows
    const u16* qbase  = q  + ((size_t)(b * 16 + h)  * 512 + q0) * 64;
    const u16* kbase  = k  + (size_t)(b * 4 + kvh) * (512 * 64);
    const u16* vtbase = vt + (size_t)(b * 4 + kvh) * (64 * 512);

    // Q fragments (row = l15, d-chunks 0/1)
    const bf16x8 qf0 = *(const bf16x8*)(qbase + (size_t)l15 * 64 + g * 8);
    const bf16x8 qf1 = *(const bf16x8*)(qbase + (size_t)l15 * 64 + 32 + g * 8);

    f32x4 so[4];                            // O acc, dtiles of 16
#pragma unroll
    for (int dt = 0; dt < 4; ++dt) so[dt] = (f32x4){0.f, 0.f, 0.f, 0.f};
    float m[4]    = {-1e30f, -1e30f, -1e30f, -1e30f};
    float lsum[4] = {0.f, 0.f, 0.f, 0.f};
    const int qrow = q0 + g * 4;            // + r = this lane's q rows (D layout)
    u16* pw = &plds[w][0];

    const int nch = ((q0 + 15) >> 5) + 1;   // causal: 32-wide kv chunks
    for (int c = 0; c < nch; ++c) {
        const int kc = c << 5;
        // K fragments: kv-tiles lo (kc..kc+15) and hi (kc+16..kc+31)
        const u16* kp = kbase + (size_t)(kc + l15) * 64 + g * 8;
        const bf16x8 kl0 = *(const bf16x8*)(kp);
        const bf16x8 kl1 = *(const bf16x8*)(kp + 32);
        const bf16x8 kh0 = *(const bf16x8*)(kp + 16 * 64);
        const bf16x8 kh1 = *(const bf16x8*)(kp + 16 * 64 + 32);
        f32x4 slo = (f32x4){0.f, 0.f, 0.f, 0.f};
        f32x4 shi = (f32x4){0.f, 0.f, 0.f, 0.f};
        slo = __builtin_amdgcn_mfma_f32_16x16x32_bf16(qf0, kl0, slo, 0, 0, 0);
        slo = __builtin_amdgcn_mfma_f32_16x16x32_bf16(qf1, kl1, slo, 0, 0, 0);
        shi = __builtin_amdgcn_mfma_f32_16x16x32_bf16(qf0, kh0, shi, 0, 0, 0);
        shi = __builtin_amdgcn_mfma_f32_16x16x32_bf16(qf1, kh1, shi, 0, 0, 0);
        // V^T fragments for PV (issue early; consumed after softmax)
        bf16x8 vf[4];
#pragma unroll
        for (int dt = 0; dt < 4; ++dt)
            vf[dt] = *(const bf16x8*)(vtbase + (size_t)(dt * 16 + l15) * 512 + kc + g * 8);
        // causal mask (D layout: col=l15=kv, row=qrow+r)
        const int kvlo = kc + l15, kvhi = kvlo + 16;
#pragma unroll
        for (int r = 0; r < 4; ++r) {
            const int qg = qrow + r;
            if (kvlo > qg) slo[r] = -1e30f;
            if (kvhi > qg) shi[r] = -1e30f;
        }
        // online softmax (row reduce across the 16 col-lanes)
        float pe0[4], pe1[4], alpha[4];
#pragma unroll
        for (int r = 0; r < 4; ++r) {
            float t = fmaxf(slo[r], shi[r]);
#pragma unroll
            for (int mm = 8; mm > 0; mm >>= 1) t = fmaxf(t, __shfl_xor(t, mm, 64));
            const float mnew = fmaxf(m[r], t);
            pe0[r] = __expf(slo[r] - mnew);
            pe1[r] = __expf(shi[r] - mnew);
            float cs = pe0[r] + pe1[r];
#pragma unroll
            for (int mm = 8; mm > 0; mm >>= 1) cs += __shfl_xor(cs, mm, 64);
            alpha[r] = __expf(m[r] - mnew);
            lsum[r] = lsum[r] * alpha[r] + cs;
            m[r] = mnew;
        }
#pragma unroll
        for (int dt = 0; dt < 4; ++dt)
#pragma unroll
            for (int r = 0; r < 4; ++r) so[dt][r] *= alpha[r];
        // P -> LDS (row = g*4+r, cols l15 / l15+16), then read back as A-frag
#pragma unroll
        for (int r = 0; r < 4; ++r) {
            pw[(g * 4 + r) * 40 + l15]      = bf16r(pe0[r]);
            pw[(g * 4 + r) * 40 + 16 + l15] = bf16r(pe1[r]);
        }
        asm volatile("s_waitcnt lgkmcnt(0)" ::: "memory");  // cross-lane P visibility
        __builtin_amdgcn_sched_barrier(0);                  // rule #18 (cross-lane dep
                                                            // invisible to compiler)
        const bf16x8 pf = *(const bf16x8*)(pw + l15 * 40 + g * 8);
#pragma unroll
        for (int dt = 0; dt < 4; ++dt)
            so[dt] = __builtin_amdgcn_mfma_f32_16x16x32_bf16(pf, vf[dt], so[dt], 0, 0, 0);
        asm volatile("" ::: "memory");      // keep next iter's P writes after this read
    }
    // epilogue: y[b][t][h*64+d]
#pragma unroll
    for (int dt = 0; dt < 4; ++dt) {
#pragma unroll
        for (int r = 0; r < 4; ++r) {
            const int qg = qrow + r;
            y[(size_t)(b * 512 + qg) * 1024 + h * 64 + dt * 16 + l15] =
                bf16r(so[dt][r] / lsum[r]);
        }
    }
}

// ---------- 128-tile bf16 MFMA GEMM (qkv/proj/mlp) ----------
// EPI: 0 = +bias -> f32 | 1 = +bias+resid -> f32
template <int EPI>
__global__ __launch_bounds__(256) void gemm_kernel(const u16* __restrict__ A,
                                                   const u16* __restrict__ Bt,
                                                   const float* __restrict__ bias,
                                                   const float* __restrict__ resid,
                                                   float* __restrict__ outF,
                                                   u16* __restrict__ outU,
                                                   int N, int K) {
    __shared__ __align__(16) u16 lA[3][4096];   // 3 bufs x (4 kc-chunks x 128 rows x 8 bf16)
    __shared__ __align__(16) u16 lB[3][4096];
    const int tid = threadIdx.x;
    const int wid = tid >> 6, lane = tid & 63;

    // --- GROUP_M=8 swizzle (gridDim.y == 32 for all our GEMMs) ---
    const int ntx = gridDim.x;
    const int bid = blockIdx.y * ntx + blockIdx.x;
    const int gsz = ntx << 3;                   // 8 m-tiles x all n-tiles
    const int g   = bid / gsz;
    const int rem = bid - g * gsz;
    const int m0 = ((g << 3) + (rem & 7)) << 7; // m fastest within group
    const int n0 = (rem >> 3) << 7;

    const int wm = (wid >> 1) << 6, wn = (wid & 1) << 6;
    const int kc = lane >> 4, l15 = lane & 15;

    const u16* gA = A  + (size_t)(m0 + (tid & 127)) * K + ((tid >> 7) << 3);
    const u16* gB = Bt + (size_t)(n0 + (tid & 127)) * K + ((tid >> 7) << 3);
    const int wofs = wid << 9;

    f32x4 acc[4][4];
#pragma unroll
    for (int i = 0; i < 4; ++i)
#pragma unroll
        for (int j = 0; j < 4; ++j) acc[i][j] = (f32x4){0.f, 0.f, 0.f, 0.f};

    auto stage = [&](int c) {
        glds16(gA, &lA[c][wofs]); glds16(gA + 16, &lA[c][2048 + wofs]);
        glds16(gB, &lB[c][wofs]); glds16(gB + 16, &lB[c][2048 + wofs]);
        gA += 32; gB += 32;
    };
    auto compute = [&](int c) {
        const bf16x8* lAv = (const bf16x8*)lA[c];
        const bf16x8* lBv = (const bf16x8*)lB[c];
        bf16x8 af[4], bfr[4];
#pragma unroll
        for (int tt = 0; tt < 4; ++tt) {
            af[tt]  = lAv[kc * 128 + wm + tt * 16 + l15];
            bfr[tt] = lBv[kc * 128 + wn + tt * 16 + l15];
        }
        __builtin_amdgcn_s_setprio(1);
#pragma unroll
        for (int tm = 0; tm < 4; ++tm)
#pragma unroll
            for (int tn = 0; tn < 4; ++tn)
                acc[tm][tn] = __builtin_amdgcn_mfma_f32_16x16x32_bf16(af[tm], bfr[tn],
                                                                      acc[tm][tn], 0, 0, 0);
        __builtin_amdgcn_s_setprio(0);
    };

    const int nk = K >> 5;
    stage(0); stage(1);

    int cb = 0, sb = 2;
    for (int t = 0; t < nk - 1; ++t) {
        asm volatile("s_waitcnt vmcnt(4)" ::: "memory");
        __builtin_amdgcn_s_barrier();
        if (t + 2 < nk) stage(sb);
        compute(cb);
        cb = (cb == 2) ? 0 : cb + 1;
        sb = (sb == 2) ? 0 : sb + 1;
    }
    asm volatile("s_waitcnt vmcnt(0)" ::: "memory");
    __builtin_amdgcn_s_barrier();
    compute(cb);

    const int rbase = (lane >> 4) << 2;
#pragma unroll
    for (int tn = 0; tn < 4; ++tn) {
        const int gc = n0 + wn + tn * 16 + l15;
        float bv = 0.f;
        if (EPI != 3) bv = bias[gc];
#pragma unroll
        for (int tm = 0; tm < 4; ++tm) {
#pragma unroll
            for (int r = 0; r < 4; ++r) {
                const int gr = m0 + wm + tm * 16 + rbase + r;
                const size_t idx = (size_t)gr * N + gc;
                float vv = acc[tm][tn][r] + bv;
                if (EPI == 1) vv += resid[idx];
                if (EPI == 2) {
                    const float gl = 0.5f * vv * (1.f + fast_erf(vv * 0.70710678118654752f));
                    outU[idx] = bf16r(gl);
                } else {
                    outF[idx] = vv;
                }
            }
        }
    }
}

// ---------- 256x256 8-PHASE bf16 MFMA GEMM (fc + lm_head) ----------
// Best measured lm_head structure (R7/R8: 474-476 us; 4ph-merged and occ-2 both
// regressed). PHASE_B loads af[0..3]+bfr[4] (B-frags carried in regs); PHASE_R
// loads af[4..7] and reuses bfr (LDS reads 32->24 per K-tile).
// XCD-supertile mapping (R7, measured FETCH 530->193 MB): XCD owns m-strip
// (A panels L2-resident); 4m x 8n concurrent supertile -> B 4-way temporal reuse.
// Epilogue R11: f/r-outer n-inner -> each lane stores its row's 4 consecutive
// 64B segments back-to-back (256B contiguous per 16-lane group) for full-line
// write-combining at L2 (WRITE_SIZE 640 MB vs 524 compulsory).
#define PHASE_B(c, kh, STAGE, WV)                                              \
  {                                                                            \
    bf16x8 af[4];                                                              \
    _Pragma("unroll") for (int j = 0; j < 4; ++j)                              \
      af[j] = smv[(c) * 4096 + (kh) * 512 + aoff + j * 16];                    \
    _Pragma("unroll") for (int n = 0; n < 4; ++n)                              \
      bfr[n] = smv[(c) * 4096 + (kh) * 512 + boff + n * 16];                   \
    STAGE;                                                                     \
    __builtin_amdgcn_s_barrier();                                              \
    asm volatile("s_waitcnt lgkmcnt(0)" ::: "memory");                         \
    __builtin_amdgcn_s_setprio(1);                                             \
    _Pragma("unroll") for (int j = 0; j < 4; ++j)                              \
      _Pragma("unroll") for (int n = 0; n < 4; ++n)                            \
        acc[j][n] = __builtin_amdgcn_mfma_f32_16x16x32_bf16(                   \
            af[j], bfr[n], acc[j][n], 0, 0, 0);                                \
    __builtin_amdgcn_s_setprio(0);                                             \
    if (WV) asm volatile("s_waitcnt vmcnt(4)" ::: "memory");                   \
    __builtin_amdgcn_s_barrier();                                              \
  }
#define PHASE_R(c, kh, STAGE, WV)                                              \
  {                                                                            \
    bf16x8 af[4];                                                              \
    _Pragma("unroll") for (int j = 0; j < 4; ++j)                              \
      af[j] = smv[(c) * 4096 + (kh) * 512 + aoff + (4 + j) * 16];              \
    STAGE;                                                                     \
    __builtin_amdgcn_s_barrier();                                              \
    asm volatile("s_waitcnt lgkmcnt(0)" ::: "memory");                         \
    __builtin_amdgcn_s_setprio(1);                                             \
    _Pragma("unroll") for (int j = 0; j < 4; ++j)                              \
      _Pragma("unroll") for (int n = 0; n < 4; ++n)                            \
        acc[4 + j][n] = __builtin_amdgcn_mfma_f32_16x16x32_bf16(               \
            af[j], bfr[n], acc[4 + j][n], 0, 0, 0);                            \
    __builtin_amdgcn_s_setprio(0);                                             \
    if (WV) asm volatile("s_waitcnt vmcnt(4)" ::: "memory");                   \
    __builtin_amdgcn_s_barrier();                                              \
  }

template <int EPI>
__global__ __launch_bounds__(512) void gemm256_kernel(const u16* __restrict__ A,
                                                      const u16* __restrict__ Bt,
                                                      const float* __restrict__ bias,
                                                      float* __restrict__ outF,
                                                      u16* __restrict__ outU,
                                                      int N, int K) {
    const int NTt = N >> 8;                     // n-tiles (125 lm_head, 16 fc)
    const int bid = blockIdx.x;
    const int xcd = bid & 7;
    const int window = bid >> 8;
    const int pos = (bid >> 3) & 31;            // 32 concurrent slots per XCD
    const int strip = xcd & 3;                  // XCD's fixed m-strip (4 m-tiles)
    const int scol = (xcd >> 2) + (window << 1);
    const int mt = (strip << 2) + (pos & 3);    // m-minor within supertile
    const int nt = (scol << 3) + (pos >> 2);
    if (nt >= NTt) return;                      // grid padding (partial last scol)
    const int m0 = mt << 8, n0 = nt << 8;

    __shared__ __align__(16) u16 sm[65536];     // 128 KiB: Ab0|Bb0|Ab1|Bb1, 2048 units each
    const int tid = threadIdx.x;
    const int wid = tid >> 6, lane = tid & 63;
    const int wr = wid >> 2, wc = wid & 3;      // 2M x 4N waves, wave tile 128x64
    const int kc = lane >> 4, l15 = lane & 15;

    const int s_kc  = wid >> 1;
    const int s_row = ((wid & 1) << 6) + lane;
    const int s_u   = wid << 6;

    const u16* gA0 = A  + (size_t)(m0 + s_row) * K + s_kc * 8;
    const u16* gA1 = gA0 + (size_t)128 * K;
    const u16* gB0 = Bt + (size_t)(n0 + s_row) * K + s_kc * 8;
    const u16* gB1 = gB0 + (size_t)128 * K;

    f32x4 acc[8][4];
#pragma unroll
    for (int i = 0; i < 8; ++i)
#pragma unroll
        for (int j = 0; j < 4; ++j) acc[i][j] = (f32x4){0.f, 0.f, 0.f, 0.f};

    const bf16x8* smv = (const bf16x8*)sm;
    const int aoff = wr * 1024 + kc * 128 + l15;
    const int boff = 2048 + (wc >> 1) * 1024 + kc * 128 + ((wc & 1) << 6) + l15;

    auto stA = [&](int kt, int kh, int c) {
        const int ko = kt * 64 + kh * 32;
        const int ub = c * 4096 + kh * 512 + s_u;
        glds16(gA0 + ko, &sm[(size_t)ub * 8]);
        glds16(gA1 + ko, &sm[(size_t)(ub + 1024) * 8]);
    };
    auto stB = [&](int kt, int kh, int c) {
        const int ko = kt * 64 + kh * 32;
        const int ub = 2048 + c * 4096 + kh * 512 + s_u;
        glds16(gB0 + ko, &sm[(size_t)ub * 8]);
        glds16(gB1 + ko, &sm[(size_t)(ub + 1024) * 8]);
    };

    const int nk = K >> 6;
    stA(0, 0, 0); stB(0, 0, 0);
    stA(0, 1, 0); stB(0, 1, 0);
    stA(1, 0, 1); stB(1, 0, 1);
    asm volatile("s_waitcnt vmcnt(4)" ::: "memory");
    __builtin_amdgcn_s_barrier();

    bf16x8 bfr[4];                              // B-frags carried across mh pair
    const int niter = nk >> 1;
    for (int i = 0; i < niter; ++i) {
        const int t1 = 2 * i + 1;
        const int t2 = (2 * i + 2 < nk) ? 2 * i + 2 : nk - 1;
        const int t3 = (2 * i + 3 < nk) ? 2 * i + 3 : nk - 1;
        PHASE_B(0, 0, stA(t1, 1, 1), 0)
        PHASE_R(0, 0, stB(t1, 1, 1), 0)
        PHASE_B(0, 1, stA(t2, 0, 0), 0)
        PHASE_R(0, 1, stB(t2, 0, 0), 1)
        PHASE_B(1, 0, stA(t2, 1, 0), 0)
        PHASE_R(1, 0, stB(t2, 1, 0), 0)
        PHASE_B(1, 1, stA(t3, 0, 1), 0)
        PHASE_R(1, 1, stB(t3, 0, 1), 1)
    }
    asm volatile("s_waitcnt vmcnt(0)" ::: "memory");

    // epilogue: row-contiguous store order (write-combining)
    const int rbase = (lane >> 4) << 2;
    float bv[4];
#pragma unroll
    for (int n = 0; n < 4; ++n)
        bv[n] = (EPI == 2) ? bias[n0 + wc * 64 + n * 16 + l15] : 0.f;
#pragma unroll
    for (int f = 0; f < 8; ++f) {
#pragma unroll
        for (int r = 0; r < 4; ++r) {
            const int gr = m0 + wr * 128 + f * 16 + rbase + r;
            float* orow = outF + (size_t)gr * N;
            u16*   urow = outU + (size_t)gr * N;
#pragma unroll
            for (int n = 0; n < 4; ++n) {
                const int gc = n0 + wc * 64 + n * 16 + l15;
                const float vv = acc[f][n][r] + bv[n];
                if (EPI == 2) {
                    const float gl = 0.5f * vv * (1.f + fast_erf(vv * 0.70710678118654752f));
                    urow[gc] = bf16r(gl);
                } else {
                    orow[gc] = vv;
                }
            }
        }
    }
}

// ---------- host ----------
extern "C" void kernel_launch(void* const* d_in, const int* in_sizes, int n_in,
                              void* d_out, int out_size, void* d_ws, size_t ws_size,
                              hipStream_t stream) {
    const int*   ids      = (const int*)d_in[0];
    const float* wte      = (const float*)d_in[1];
    const float* ln1_g    = (const float*)d_in[2];
    const float* ln1_b    = (const float*)d_in[3];
    const float* c_attn_w = (const float*)d_in[4];
    const float* c_attn_b = (const float*)d_in[5];
    const float* c_proj_w = (const float*)d_in[6];
    const float* c_proj_b = (const float*)d_in[7];
    const float* ln2_g    = (const float*)d_in[8];
    const float* ln2_b    = (const float*)d_in[9];
    const float* fc_w     = (const float*)d_in[10];
    const float* fc_b     = (const float*)d_in[11];
    const float* proj_w   = (const float*)d_in[12];
    const float* proj_b   = (const float*)d_in[13];
    const float* lnf_g    = (const float*)d_in[14];
    const float* lnf_b    = (const float*)d_in[15];
    const float* lm_w     = (const float*)d_in[16];
    float* out = (float*)d_out;

    char* w = (char*)d_ws;
    auto take = [&](size_t bytes) { void* p = (void*)w; w += (bytes + 255) & ~(size_t)255; return p; };
    u16*   wqkvT = (u16*)take((size_t)Lz * QKVz * Dz * 2);   // [L][1536][1024]
    u16*   wprojT= (u16*)take((size_t)Lz * Dz * Dz * 2);     // [L][1024][1024]
    u16*   wfcT  = (u16*)take((size_t)Lz * FFz * Dz * 2);    // [L][4096][1024]
    u16*   wmlpT = (u16*)take((size_t)Lz * Dz * FFz * 2);    // [L][1024][4096]
    u16*   wlmT  = (u16*)take((size_t)Vz * Dz * 2);          // [32000][1024]
    float* x     = (float*)take((size_t)Mz * Dz * 4);
    u16*   h     = (u16*)take((size_t)Mz * Dz * 2);
    float* qkv   = (float*)take((size_t)Mz * QKVz * 4);
    u16*   qb    = (u16*)take((size_t)Mz * Dz * 2);
    u16*   kb    = (u16*)take((size_t)Bz * KVHz * Tz * HDz * 2);
    u16*   vb    = (u16*)take((size_t)Bz * KVHz * Tz * HDz * 2);
    u16*   yb    = (u16*)take((size_t)Mz * Dz * 2);
    u16*   mb    = (u16*)take((size_t)Mz * FFz * 2);
    (void)ws_size; (void)in_sizes; (void)n_in; (void)out_size;

    const dim3 tb(256);
    transpose_cvt_kernel<<<dim3(QKVz / 64, Dz / 64, Lz), tb, 0, stream>>>(c_attn_w, wqkvT, Dz, QKVz);
    transpose_cvt_kernel<<<dim3(Dz / 64, Dz / 64, Lz), tb, 0, stream>>>(c_proj_w, wprojT, Dz, Dz);
    transpose_cvt_kernel<<<dim3(FFz / 64, Dz / 64, Lz), tb, 0, stream>>>(fc_w, wfcT, Dz, FFz);
    transpose_cvt_kernel<<<dim3(Dz / 64, FFz / 64, Lz), tb, 0, stream>>>(proj_w, wmlpT, FFz, Dz);
    transpose_cvt_kernel<<<dim3(Vz / 64, Dz / 64, 1), tb, 0, stream>>>(lm_w, wlmT, Dz, Vz);

    embed_kernel<<<Mz, tb, 0, stream>>>(ids, wte, x);

    // gemm256 grids: 128 * scols blocks, scols = ceil(NT/8) (even: lm 16, fc 2)
    const int fc_grid = 128 * (((FFz / 256) + 7) / 8);   // 256
    const int lm_grid = 128 * (((Vz / 256) + 7) / 8);    // 2048 (48 pad blocks exit)

    for (int l = 0; l < Lz; ++l) {
        ln_kernel<<<Mz, tb, 0, stream>>>(x, ln1_g + l * Dz, ln1_b + l * Dz, h);
        gemm_kernel<0><<<dim3(QKVz / 128, Mz / 128), tb, 0, stream>>>(
            h, wqkvT + (size_t)l * QKVz * Dz, c_attn_b + l * QKVz, nullptr, qkv, nullptr, QKVz, Dz);
        rope_split_kernel<<<Mz, tb, 0, stream>>>(qkv, qb, kb, vb);
        attn_kernel<<<Bz * Hz * (Tz / 64), tb, 0, stream>>>(qb, kb, vb, yb);
        gemm_kernel<1><<<dim3(Dz / 128, Mz / 128), tb, 0, stream>>>(
            yb, wprojT + (size_t)l * Dz * Dz, c_proj_b + l * Dz, x, x, nullptr, Dz, Dz);
        ln_kernel<<<Mz, tb, 0, stream>>>(x, ln2_g + l * Dz, ln2_b + l * Dz, h);
        gemm256_kernel<2><<<dim3(fc_grid), dim3(512), 0, stream>>>(
            h, wfcT + (size_t)l * FFz * Dz, fc_b + l * FFz, nullptr, mb, FFz, Dz);
        gemm_kernel<1><<<dim3(Dz / 128, Mz / 128), tb, 0, stream>>>(
            mb, wmlpT + (size_t)l * Dz * FFz, proj_b + l * Dz, x, x, nullptr, Dz, FFz);
    }
    ln_kernel<<<Mz, tb, 0, stream>>>(x, lnf_g, lnf_b, h);
    gemm256_kernel<3><<<dim3(lm_grid), dim3(512), 0, stream>>>(
        h, wlmT, nullptr, out, nullptr, Vz, Dz);
}